// Round 5
// baseline (218.355 us; speedup 1.0000x reference)
//
#include <hip/hip_runtime.h>
#include <math.h>

typedef _Float16 f16;
typedef _Float16 f16x4 __attribute__((ext_vector_type(4)));
typedef _Float16 f16x8 __attribute__((ext_vector_type(8)));
typedef float    f32x4 __attribute__((ext_vector_type(4)));

#define NSEQ 1024
#define CD   128
#define KSTR 136   // Kt row stride, f16 (272 B = 17*16 B: b128-aligned, 17 odd -> uniform bank-group rotation)
#define VSTR 72    // Vt^T row stride, f16 (144 B = 9*16 B: b128-aligned, 9 odd -> uniform rotation)

// Single fused kernel. Block = (bh, qblk): 4 waves x 32 q-rows = 128 q-rows.
// Per 64-key tile: raw k/v loaded to REGISTERS early (in flight under compute of the
// previous tile), Lorentz-transformed in f32, stored to LDS as:
//   Kt[key][c]   row-major  -> kf frag = ds_read_b128, ROW PERMUTED (see below)
//   Vt[c][key]   transposed -> vf frag = ds_read_b128 at [cb*16+lq][k2*32+quad*8]
// KEY-ORDER CONSISTENCY (the R4 bug): QK^T puts score for A-row i of group g at
// accumulator slot (quad*4+reg); PV consumes p[k2*8+j] as key k2*32+quad*8+j. These
// only agree if kf row i of group g holds key  keyl = (g>>1)*32 + 8*(i>>2) + 4*(g&1) + (i&3).
// Reading Kt linearly (g*16+lq) permutes keys between QK^T and PV -> absmax 2.7. The
// permuted read below makes p's key order match Vt's exactly (derivation in journal).
__global__ __launch_bounds__(256, 2)
void ipa_fused(const float* __restrict__ qg, const float* __restrict__ kg,
               const float* __restrict__ vg, const float* __restrict__ Lm,
               float* __restrict__ out)
{
    __shared__ __align__(16) f16 Kt[64 * KSTR];    // 17,408 B
    __shared__ __align__(16) f16 Vt[128 * VSTR];   // 18,432 B
    const int n = blockIdx.x;                      // 512 blocks = 64 bh x 8 qblk
    const int bh = ((n & 7) << 3) | ((n >> 3) & 7);   // XCD c <- bh octet 8c..8c+7
    const int b  = bh >> 3;
    const int tid = threadIdx.x;
    const int w = tid >> 6, lane = tid & 63, lq = lane & 15, quad = lane >> 4;
    const int qblk = n >> 6;                       // 0..7
    const int q0 = qblk * 128 + w * 32;
    const float sc2 = 0.12751744154226873f;        // (1/sqrt(128)) * log2(e)
    const int kperm = ((lq >> 2) << 3) | (lq & 3); // row permutation for kf reads

    const int krow = tid >> 2;                     // local key row this thread stages
    const int cq   = tid & 3;                      // c-quarter (32 floats)
    const float* kgb = kg + ((size_t)bh * NSEQ) * CD + cq * 32;
    const float* vgb = vg + ((size_t)bh * NSEQ) * CD + cq * 32;

    float4 kx[8], vx[8];                           // staged raw tile (t+1)

    // ---- Q: load fp32, transform (M = eta L^T eta) per-lane, scale, make frags ----
    f16x8 qf[2][4];
    #pragma unroll
    for (int u = 0; u < 2; ++u) {
        int qrow = q0 + u * 16 + lq;
        const float* Lr = Lm + ((size_t)b * NSEQ + qrow) * 16;
        const float* qp = qg + ((size_t)bh * NSEQ + qrow) * CD;
        float Lv[16];
        #pragma unroll
        for (int i = 0; i < 4; ++i) *(float4*)&Lv[i*4] = *(const float4*)(Lr + i*4);
        #pragma unroll
        for (int cs = 0; cs < 4; ++cs) {
            int c0 = cs * 32 + quad * 8;
            float4 x0 = *(const float4*)(qp + c0);
            float4 x1 = *(const float4*)(qp + c0 + 4);
            if (c0 >= 8) {
                float t0 = x0.x, t1 = -x0.y, t2 = -x0.z, t3 = -x0.w;
                float4 y;
                y.x =  (Lv[0]*t0 + Lv[4]*t1 + Lv[8] *t2 + Lv[12]*t3);
                y.y = -(Lv[1]*t0 + Lv[5]*t1 + Lv[9] *t2 + Lv[13]*t3);
                y.z = -(Lv[2]*t0 + Lv[6]*t1 + Lv[10]*t2 + Lv[14]*t3);
                y.w = -(Lv[3]*t0 + Lv[7]*t1 + Lv[11]*t2 + Lv[15]*t3);
                x0 = y;
                t0 = x1.x; t1 = -x1.y; t2 = -x1.z; t3 = -x1.w;
                y.x =  (Lv[0]*t0 + Lv[4]*t1 + Lv[8] *t2 + Lv[12]*t3);
                y.y = -(Lv[1]*t0 + Lv[5]*t1 + Lv[9] *t2 + Lv[13]*t3);
                y.z = -(Lv[2]*t0 + Lv[6]*t1 + Lv[10]*t2 + Lv[14]*t3);
                y.w = -(Lv[3]*t0 + Lv[7]*t1 + Lv[11]*t2 + Lv[15]*t3);
                x1 = y;
            }
            qf[u][cs] = (f16x8){(f16)(x0.x*sc2), (f16)(x0.y*sc2), (f16)(x0.z*sc2), (f16)(x0.w*sc2),
                                (f16)(x1.x*sc2), (f16)(x1.y*sc2), (f16)(x1.z*sc2), (f16)(x1.w*sc2)};
        }
    }

    // ---- staging helpers ----
    auto load_k = [&](int t) {
        const float* kp = kgb + ((size_t)t * 64 + krow) * CD;
        #pragma unroll
        for (int j = 0; j < 8; ++j) kx[j] = *(const float4*)(kp + j * 4);
    };
    auto load_v = [&](int t) {
        const float* vp = vgb + ((size_t)t * 64 + krow) * CD;
        #pragma unroll
        for (int j = 0; j < 8; ++j) vx[j] = *(const float4*)(vp + j * 4);
    };
    // transform staged regs with this key's L, write Kt (row-major) + Vt (transposed)
    auto xform_write = [&](int t) {
        int key = t * 64 + krow;
        const float* Lr = Lm + ((size_t)b * NSEQ + key) * 16;
        float Lv[16];
        #pragma unroll
        for (int i = 0; i < 4; ++i) *(float4*)&Lv[i*4] = *(const float4*)(Lr + i*4);
        #pragma unroll
        for (int jp = 0; jp < 4; ++jp) {
            float4 a0 = kx[jp*2], a1 = kx[jp*2+1];
            float4 b0 = vx[jp*2], b1 = vx[jp*2+1];
            if (!(cq == 0 && jp == 0)) {           // (cq==0,jp==0) covers c 0..7 = scalar passthrough
                float t0 = a0.x, t1 = -a0.y, t2 = -a0.z, t3 = -a0.w;  // K: M = L^T eta
                float4 y;
                y.x = Lv[0]*t0 + Lv[4]*t1 + Lv[8] *t2 + Lv[12]*t3;
                y.y = Lv[1]*t0 + Lv[5]*t1 + Lv[9] *t2 + Lv[13]*t3;
                y.z = Lv[2]*t0 + Lv[6]*t1 + Lv[10]*t2 + Lv[14]*t3;
                y.w = Lv[3]*t0 + Lv[7]*t1 + Lv[11]*t2 + Lv[15]*t3;
                a0 = y;
                t0 = a1.x; t1 = -a1.y; t2 = -a1.z; t3 = -a1.w;
                y.x = Lv[0]*t0 + Lv[4]*t1 + Lv[8] *t2 + Lv[12]*t3;
                y.y = Lv[1]*t0 + Lv[5]*t1 + Lv[9] *t2 + Lv[13]*t3;
                y.z = Lv[2]*t0 + Lv[6]*t1 + Lv[10]*t2 + Lv[14]*t3;
                y.w = Lv[3]*t0 + Lv[7]*t1 + Lv[11]*t2 + Lv[15]*t3;
                a1 = y;
                t0 = b0.x; t1 = -b0.y; t2 = -b0.z; t3 = -b0.w;        // V: M = eta L^T eta
                y.x =  (Lv[0]*t0 + Lv[4]*t1 + Lv[8] *t2 + Lv[12]*t3);
                y.y = -(Lv[1]*t0 + Lv[5]*t1 + Lv[9] *t2 + Lv[13]*t3);
                y.z = -(Lv[2]*t0 + Lv[6]*t1 + Lv[10]*t2 + Lv[14]*t3);
                y.w = -(Lv[3]*t0 + Lv[7]*t1 + Lv[11]*t2 + Lv[15]*t3);
                b0 = y;
                t0 = b1.x; t1 = -b1.y; t2 = -b1.z; t3 = -b1.w;
                y.x =  (Lv[0]*t0 + Lv[4]*t1 + Lv[8] *t2 + Lv[12]*t3);
                y.y = -(Lv[1]*t0 + Lv[5]*t1 + Lv[9] *t2 + Lv[13]*t3);
                y.z = -(Lv[2]*t0 + Lv[6]*t1 + Lv[10]*t2 + Lv[14]*t3);
                y.w = -(Lv[3]*t0 + Lv[7]*t1 + Lv[11]*t2 + Lv[15]*t3);
                b1 = y;
            }
            int c0 = cq * 32 + jp * 8;
            f16x8 hk = {(f16)a0.x,(f16)a0.y,(f16)a0.z,(f16)a0.w,
                        (f16)a1.x,(f16)a1.y,(f16)a1.z,(f16)a1.w};
            *(f16x8*)&Kt[krow * KSTR + c0] = hk;
            Vt[(c0+0)*VSTR + krow] = (f16)b0.x;
            Vt[(c0+1)*VSTR + krow] = (f16)b0.y;
            Vt[(c0+2)*VSTR + krow] = (f16)b0.z;
            Vt[(c0+3)*VSTR + krow] = (f16)b0.w;
            Vt[(c0+4)*VSTR + krow] = (f16)b1.x;
            Vt[(c0+5)*VSTR + krow] = (f16)b1.y;
            Vt[(c0+6)*VSTR + krow] = (f16)b1.z;
            Vt[(c0+7)*VSTR + krow] = (f16)b1.w;
        }
    };

    f32x4 oacc[2][8];
    #pragma unroll
    for (int u = 0; u < 2; ++u)
        #pragma unroll
        for (int cb = 0; cb < 8; ++cb) oacc[u][cb] = (f32x4){0.f, 0.f, 0.f, 0.f};
    float mrun[2] = {-1e30f, -1e30f}, lrun[2] = {0.f, 0.f};

    // prologue: tile 0 through regs -> LDS
    load_k(0); load_v(0);
    xform_write(0);
    __syncthreads();

    for (int t = 0; t < 16; ++t) {                 // 64 keys per tile
        // kf + QK^T (issue next tile's k loads after kf regs are consumed)
        f16x8 kf[4][4];
        #pragma unroll
        for (int g = 0; g < 4; ++g) {
            int keyl = ((g >> 1) << 5) + ((g & 1) << 2) + kperm;   // permuted row (see header)
            #pragma unroll
            for (int cs = 0; cs < 4; ++cs)
                kf[g][cs] = *(const f16x8*)&Kt[keyl * KSTR + cs * 32 + quad * 8];
        }

        f32x4 s[2][4];
        #pragma unroll
        for (int u = 0; u < 2; ++u)
            #pragma unroll
            for (int g = 0; g < 4; ++g) s[u][g] = (f32x4){0.f, 0.f, 0.f, 0.f};
        #pragma unroll
        for (int g = 0; g < 4; ++g)
            #pragma unroll
            for (int cs = 0; cs < 4; ++cs) {
                s[0][g] = __builtin_amdgcn_mfma_f32_16x16x32_f16(kf[g][cs], qf[0][cs], s[0][g], 0, 0, 0);
                s[1][g] = __builtin_amdgcn_mfma_f32_16x16x32_f16(kf[g][cs], qf[1][cs], s[1][g], 0, 0, 0);
            }
        if (t < 15) load_k(t + 1);                 // in flight under softmax+PV

        // exp2-domain online softmax; l-sum kept per-lane (quad-reduced once in epilogue)
        f16x8 pf[2][2];
        #pragma unroll
        for (int u = 0; u < 2; ++u) {
            float mx = -1e30f;
            #pragma unroll
            for (int g = 0; g < 4; ++g)
                mx = fmaxf(mx, fmaxf(fmaxf(s[u][g].x, s[u][g].y), fmaxf(s[u][g].z, s[u][g].w)));
            mx = fmaxf(mx, __shfl_xor(mx, 16, 64));
            mx = fmaxf(mx, __shfl_xor(mx, 32, 64));
            float mnew = fmaxf(mrun[u], mx);
            // defer-rescale (bit-exact): when no lane sees a new max, alpha==1 exactly
            if (!__all(mx <= mrun[u])) {
                float alpha = exp2f(mrun[u] - mnew);
                lrun[u] *= alpha;
                #pragma unroll
                for (int cb = 0; cb < 8; ++cb) oacc[u][cb] *= alpha;
                mrun[u] = mnew;
            }
            float p[16], rs = 0.f;
            #pragma unroll
            for (int g = 0; g < 4; ++g) {
                p[g*4+0] = exp2f(s[u][g].x - mnew);
                p[g*4+1] = exp2f(s[u][g].y - mnew);
                p[g*4+2] = exp2f(s[u][g].z - mnew);
                p[g*4+3] = exp2f(s[u][g].w - mnew);
                rs += (p[g*4+0] + p[g*4+1]) + (p[g*4+2] + p[g*4+3]);
            }
            lrun[u] += rs;                         // per-lane partial; quad-sum at epilogue
            pf[u][0] = (f16x8){(f16)p[0],(f16)p[1],(f16)p[2],(f16)p[3],(f16)p[4],(f16)p[5],(f16)p[6],(f16)p[7]};
            pf[u][1] = (f16x8){(f16)p[8],(f16)p[9],(f16)p[10],(f16)p[11],(f16)p[12],(f16)p[13],(f16)p[14],(f16)p[15]};
        }
        if (t < 15) load_v(t + 1);                 // in flight under PV

        f16x8 vf[2][8];
        #pragma unroll
        for (int k2 = 0; k2 < 2; ++k2)
            #pragma unroll
            for (int cb = 0; cb < 8; ++cb)
                vf[k2][cb] = *(const f16x8*)&Vt[(cb * 16 + lq) * VSTR + k2 * 32 + quad * 8];
        #pragma unroll
        for (int k2 = 0; k2 < 2; ++k2)
            #pragma unroll
            for (int cb = 0; cb < 8; ++cb) {
                oacc[0][cb] = __builtin_amdgcn_mfma_f32_16x16x32_f16(vf[k2][cb], pf[0][k2], oacc[0][cb], 0, 0, 0);
                oacc[1][cb] = __builtin_amdgcn_mfma_f32_16x16x32_f16(vf[k2][cb], pf[1][k2], oacc[1][cb], 0, 0, 0);
            }

        if (t < 15) {
            __syncthreads();                       // all waves done reading tile t
            xform_write(t + 1);                    // regs (vmcnt-waited by data dep) -> LDS
            __syncthreads();                       // tile t+1 ready
        }
    }

    // ---- epilogue: quad-reduce l, normalize, final frame transform (M = L), store ----
    #pragma unroll
    for (int u = 0; u < 2; ++u) {
        float l = lrun[u];
        l += __shfl_xor(l, 16, 64);
        l += __shfl_xor(l, 32, 64);
        float invl = 1.0f / l;
        int qrow = q0 + u * 16 + lq;
        const float* Lr = Lm + ((size_t)b * NSEQ + qrow) * 16;
        float* ob = out + ((size_t)bh * NSEQ + qrow) * CD;
        #pragma unroll
        for (int cb = 0; cb < 8; ++cb) {
            int c0 = cb * 16 + quad * 4;
            float o0 = oacc[u][cb].x*invl, o1 = oacc[u][cb].y*invl;
            float o2 = oacc[u][cb].z*invl, o3 = oacc[u][cb].w*invl;
            float4 r;
            if (c0 >= 8) {
                r.x = Lr[0] *o0 + Lr[1] *o1 + Lr[2] *o2 + Lr[3] *o3;
                r.y = Lr[4] *o0 + Lr[5] *o1 + Lr[6] *o2 + Lr[7] *o3;
                r.z = Lr[8] *o0 + Lr[9] *o1 + Lr[10]*o2 + Lr[11]*o3;
                r.w = Lr[12]*o0 + Lr[13]*o1 + Lr[14]*o2 + Lr[15]*o3;
            } else {
                r.x = o0; r.y = o1; r.z = o2; r.w = o3;
            }
            *(float4*)(ob + c0) = r;
        }
    }
}

extern "C" void kernel_launch(void* const* d_in, const int* in_sizes, int n_in,
                              void* d_out, int out_size, void* d_ws, size_t ws_size,
                              hipStream_t stream) {
    const float* q = (const float*)d_in[0];
    const float* k = (const float*)d_in[1];
    const float* v = (const float*)d_in[2];
    const float* L = (const float*)d_in[3];
    float* o = (float*)d_out;
    ipa_fused<<<512, 256, 0, stream>>>(q, k, v, L, o);
}

// Round 6
// 196.530 us; speedup vs baseline: 1.1110x; 1.1110x over previous
//
#include <hip/hip_runtime.h>
#include <math.h>

typedef _Float16 f16;
typedef _Float16 f16x4 __attribute__((ext_vector_type(4)));
typedef _Float16 f16x8 __attribute__((ext_vector_type(8)));
typedef float    f32x4 __attribute__((ext_vector_type(4)));

typedef const __attribute__((address_space(1))) void gv_t;   // global
typedef __attribute__((address_space(3))) void lv_t;         // LDS

#define NSEQ 1024
#define CD   128
#define LT   136   // pre-kernel LDS f16 row stride (272 B = 17*16 B, keeps b128 alignment)

// khs: [bh][g16 0..63][cs 0..3][lane 0..63][j 0..7]   (131072 f16 per bh)
//   value = Ktr[key = (g16>>1)*32 + 8*(lq>>2) + 4*(g16&1) + (lq&3)][c = cs*32+quad*8+j]
// vhs: [bh][k32 0..31][cb 0..7][lane 0..63][j 0..7]
//   value = Vtr[key = k32*32 + quad*8 + j][c = cb*16 + lq]
// Both are exact MFMA fragment order AND exact linear order for global_load_lds staging.
// With 32-key attn tiles (one g16 PAIR + one k32), the QK^T score slot (quad*4+r) of
// group g holds key_local = quad*8 + g*4 + r, so pf[j=g*4+r] = p[g*4+r] feeds PV's
// B-operand (key = quad*8 + j) with NO permutation.

__global__ __launch_bounds__(256)
void ipa_pre(const float* __restrict__ kg, const float* __restrict__ vg,
             const float* __restrict__ Lm, f16* __restrict__ khs, f16* __restrict__ vhs)
{
    __shared__ float LL[64 * 16];
    __shared__ __align__(16) f16 Kt[64 * LT];
    __shared__ __align__(16) f16 Vt[64 * LT];
    const int bx = blockIdx.x, nt = blockIdx.y, tid = threadIdx.x;
    const int bh = ((bx & 7) << 3) | (bx >> 3);   // XCD x <-> bh 8x..8x+7 (matches attn)
    const int b  = bh >> 3;
    const float* Lb = Lm + ((size_t)b * NSEQ + nt * 64) * 16;
    for (int t = tid; t < 64 * 16; t += 256) LL[t] = Lb[t];
    __syncthreads();

    const size_t base = ((size_t)bh * NSEQ + nt * 64) * CD;
    #pragma unroll
    for (int it = 0; it < 8; ++it) {
        int g = it * 256 + tid;
        int row = g >> 5, cg = g & 31;
        size_t idx = base + row * CD + cg * 4;
        const float* Lr = &LL[row * 16];
        float4 xk = *(const float4*)(kg + idx);
        float4 xv = *(const float4*)(vg + idx);
        float4 yk = xk, yv = xv;
        if (cg >= 2) {
            float t0 = xk.x, t1 = -xk.y, t2 = -xk.z, t3 = -xk.w;   // K: M = L^T eta
            yk.x = Lr[0]*t0 + Lr[4]*t1 + Lr[8] *t2 + Lr[12]*t3;
            yk.y = Lr[1]*t0 + Lr[5]*t1 + Lr[9] *t2 + Lr[13]*t3;
            yk.z = Lr[2]*t0 + Lr[6]*t1 + Lr[10]*t2 + Lr[14]*t3;
            yk.w = Lr[3]*t0 + Lr[7]*t1 + Lr[11]*t2 + Lr[15]*t3;
            t0 = xv.x; t1 = -xv.y; t2 = -xv.z; t3 = -xv.w;         // V: M = eta L^T eta
            yv.x =  (Lr[0]*t0 + Lr[4]*t1 + Lr[8] *t2 + Lr[12]*t3);
            yv.y = -(Lr[1]*t0 + Lr[5]*t1 + Lr[9] *t2 + Lr[13]*t3);
            yv.z = -(Lr[2]*t0 + Lr[6]*t1 + Lr[10]*t2 + Lr[14]*t3);
            yv.w = -(Lr[3]*t0 + Lr[7]*t1 + Lr[11]*t2 + Lr[15]*t3);
        }
        f16x4 hk = {(f16)yk.x, (f16)yk.y, (f16)yk.z, (f16)yk.w};
        f16x4 hv = {(f16)yv.x, (f16)yv.y, (f16)yv.z, (f16)yv.w};
        *(f16x4*)&Kt[row * LT + cg * 4] = hk;
        *(f16x4*)&Vt[row * LT + cg * 4] = hv;
    }
    __syncthreads();

    // staged K out (b128 LDS read -> fully coalesced global store)
    f16* kout = khs + (size_t)bh * 131072 + (size_t)nt * 4 * 4 * 512;
    #pragma unroll
    for (int it = 0; it < 4; ++it) {
        int slot = it * 256 + tid;                 // (g16l, cs, L)
        int g16l = slot >> 8, cs = (slot >> 6) & 3, L = slot & 63;
        int lq = L & 15, quad = L >> 4;
        int keyl = ((g16l >> 1) << 5) + ((lq >> 2) << 3) + ((g16l & 1) << 2) + (lq & 3);
        f16x8 kv = *(const f16x8*)&Kt[keyl * LT + cs * 32 + quad * 8];
        *(f16x8*)(kout + (g16l * 4 + cs) * 512 + L * 8) = kv;
    }
    // staged V^T out (scalar LDS column reads -> coalesced global store)
    f16* vout = vhs + (size_t)bh * 131072 + (size_t)nt * 2 * 8 * 512;
    #pragma unroll
    for (int it = 0; it < 4; ++it) {
        int slot = it * 256 + tid;                 // (k32l, cb, L)
        int k32l = slot >> 9, cb = (slot >> 6) & 7, L = slot & 63;
        int lq = L & 15, quad = L >> 4;
        int c = cb * 16 + lq;
        f16x8 o;
        #pragma unroll
        for (int j = 0; j < 8; ++j)
            o[j] = Vt[(k32l * 32 + quad * 8 + j) * LT + c];
        *(f16x8*)(vout + (k32l * 8 + cb) * 512 + L * 8) = o;
    }
}

// ---------------- attention: low-register flash, 1 q-tile/wave, 32-key tiles ----------------
// R5 finding: every prior variant ran at ~2 waves/SIMD because unified VGPR+AGPR footprint
// was ~250-270 (2u q-tiles + full kf/vf arrays live). This version: 16 q-rows/wave, 32-key
// K/V tiles, fragment live-ranges confined to the MFMA loops. Target <=130 regs -> 3-4
// waves/SIMD. LDS 32 KB/block -> 4 blocks/CU. Grid 1024 x 4 waves = 16 waves/CU available.
__global__ __launch_bounds__(256, 2)
void ipa_attn(const float* __restrict__ qg, const f16* __restrict__ khs,
              const f16* __restrict__ vhs, const float* __restrict__ Lm,
              float* __restrict__ out)
{
    __shared__ __align__(16) f16 sK[2][4096];   // 8 KB per buffer (32 keys x 128 c)
    __shared__ __align__(16) f16 sV[2][4096];
    const int n = blockIdx.x;                   // 1024 blocks = 64 bh x 16 qblk
    const int bh = ((n & 7) << 3) | ((n >> 3) & 7);   // XCD-local bh octet (matches pre)
    const int b  = bh >> 3;
    const int tid = threadIdx.x;
    const int w = tid >> 6, lane = tid & 63, lq = lane & 15, quad = lane >> 4;
    const int qblk = n >> 6;                    // 0..15
    const int q0 = qblk * 64 + w * 16;          // wave owns 16 q-rows
    const f16* kbh = khs + (size_t)bh * 131072;
    const f16* vbh = vhs + (size_t)bh * 131072;
    const float sc2 = 0.12751744154226873f;     // (1/sqrt(128)) * log2(e)

    // stage one 32-key tile (8 KB K + 8 KB V); 2 x 1KB gl_lds per wave per tensor
    auto stage = [&](int nb, int it) {
        const char* kp = (const char*)(kbh + (size_t)it * 4096);
        const char* vp = (const char*)(vbh + (size_t)it * 4096);
        char* kd = (char*)&sK[nb][0];
        char* vd = (char*)&sV[nb][0];
        #pragma unroll
        for (int j = 0; j < 2; ++j) {
            int off = (w * 2 + j) * 1024;       // wave-uniform LDS dest; per-lane global src
            __builtin_amdgcn_global_load_lds((gv_t*)(kp + off + lane * 16),
                                             (lv_t*)(kd + off), 16, 0, 0);
            __builtin_amdgcn_global_load_lds((gv_t*)(vp + off + lane * 16),
                                             (lv_t*)(vd + off), 16, 0, 0);
        }
    };

    // ---- Q: load fp32, transform (M = eta L^T eta), scale, frags (16 rows) ----
    f16x8 qf[4];
    {
        int qrow = q0 + lq;
        const float* Lr = Lm + ((size_t)b * NSEQ + qrow) * 16;
        const float* qp = qg + ((size_t)bh * NSEQ + qrow) * CD;
        float Lv[16];
        #pragma unroll
        for (int i = 0; i < 4; ++i) *(float4*)&Lv[i*4] = *(const float4*)(Lr + i*4);
        #pragma unroll
        for (int cs = 0; cs < 4; ++cs) {
            int c0 = cs * 32 + quad * 8;
            float4 x0 = *(const float4*)(qp + c0);
            float4 x1 = *(const float4*)(qp + c0 + 4);
            if (c0 >= 8) {
                float t0 = x0.x, t1 = -x0.y, t2 = -x0.z, t3 = -x0.w;
                float4 y;
                y.x =  (Lv[0]*t0 + Lv[4]*t1 + Lv[8] *t2 + Lv[12]*t3);
                y.y = -(Lv[1]*t0 + Lv[5]*t1 + Lv[9] *t2 + Lv[13]*t3);
                y.z = -(Lv[2]*t0 + Lv[6]*t1 + Lv[10]*t2 + Lv[14]*t3);
                y.w = -(Lv[3]*t0 + Lv[7]*t1 + Lv[11]*t2 + Lv[15]*t3);
                x0 = y;
                t0 = x1.x; t1 = -x1.y; t2 = -x1.z; t3 = -x1.w;
                y.x =  (Lv[0]*t0 + Lv[4]*t1 + Lv[8] *t2 + Lv[12]*t3);
                y.y = -(Lv[1]*t0 + Lv[5]*t1 + Lv[9] *t2 + Lv[13]*t3);
                y.z = -(Lv[2]*t0 + Lv[6]*t1 + Lv[10]*t2 + Lv[14]*t3);
                y.w = -(Lv[3]*t0 + Lv[7]*t1 + Lv[11]*t2 + Lv[15]*t3);
                x1 = y;
            }
            qf[cs] = (f16x8){(f16)(x0.x*sc2), (f16)(x0.y*sc2), (f16)(x0.z*sc2), (f16)(x0.w*sc2),
                             (f16)(x1.x*sc2), (f16)(x1.y*sc2), (f16)(x1.z*sc2), (f16)(x1.w*sc2)};
        }
    }

    f32x4 oacc[8];
    #pragma unroll
    for (int cb = 0; cb < 8; ++cb) oacc[cb] = (f32x4){0.f, 0.f, 0.f, 0.f};
    float mrun = -1e30f, lrun = 0.f;

    stage(0, 0);

    for (int it = 0; it < 32; ++it) {               // 32 keys per iteration
        const int cur = it & 1;
        __syncthreads();                            // stage(cur) landed; prev-buf reads done
        if (it < 31) stage(cur ^ 1, it + 1);        // in flight under this tile's compute

        const f16* kb = &sK[cur][0];
        const f16* vb = &sV[cur][0];

        // QK^T: 8 MFMA, kf live-range = one iteration of this loop (8 regs)
        f32x4 s[2];
        s[0] = (f32x4){0.f, 0.f, 0.f, 0.f};
        s[1] = (f32x4){0.f, 0.f, 0.f, 0.f};
        #pragma unroll
        for (int cs = 0; cs < 4; ++cs) {
            f16x8 kf0 = *(const f16x8*)&kb[(cs    ) * 512 + lane * 8];
            f16x8 kf1 = *(const f16x8*)&kb[(cs + 4) * 512 + lane * 8];
            s[0] = __builtin_amdgcn_mfma_f32_16x16x32_f16(kf0, qf[cs], s[0], 0, 0, 0);
            s[1] = __builtin_amdgcn_mfma_f32_16x16x32_f16(kf1, qf[cs], s[1], 0, 0, 0);
        }

        // exp2-domain online softmax over 32 keys; l kept per-lane (quad-reduced at end)
        float mx = fmaxf(fmaxf(fmaxf(s[0].x, s[0].y), fmaxf(s[0].z, s[0].w)),
                         fmaxf(fmaxf(s[1].x, s[1].y), fmaxf(s[1].z, s[1].w)));
        mx = fmaxf(mx, __shfl_xor(mx, 16, 64));
        mx = fmaxf(mx, __shfl_xor(mx, 32, 64));
        float mnew = fmaxf(mrun, mx);
        // defer-rescale (bit-exact): when no lane sees a new max, alpha==1 exactly
        if (!__all(mx <= mrun)) {
            float alpha = exp2f(mrun - mnew);
            lrun *= alpha;
            #pragma unroll
            for (int cb = 0; cb < 8; ++cb) oacc[cb] *= alpha;
            mrun = mnew;
        }
        float p[8];
        p[0] = exp2f(s[0].x - mnew); p[1] = exp2f(s[0].y - mnew);
        p[2] = exp2f(s[0].z - mnew); p[3] = exp2f(s[0].w - mnew);
        p[4] = exp2f(s[1].x - mnew); p[5] = exp2f(s[1].y - mnew);
        p[6] = exp2f(s[1].z - mnew); p[7] = exp2f(s[1].w - mnew);
        lrun += ((p[0]+p[1]) + (p[2]+p[3])) + ((p[4]+p[5]) + (p[6]+p[7]));
        f16x8 pf = {(f16)p[0],(f16)p[1],(f16)p[2],(f16)p[3],
                    (f16)p[4],(f16)p[5],(f16)p[6],(f16)p[7]};

        // PV: 8 MFMA, vf live-range = one loop iteration (4 regs)
        #pragma unroll
        for (int cb = 0; cb < 8; ++cb) {
            f16x8 vf = *(const f16x8*)&vb[cb * 512 + lane * 8];
            oacc[cb] = __builtin_amdgcn_mfma_f32_16x16x32_f16(vf, pf, oacc[cb], 0, 0, 0);
        }
    }

    // ---- epilogue: quad-reduce l, normalize, final frame transform (M = L), store ----
    {
        float l = lrun;
        l += __shfl_xor(l, 16, 64);
        l += __shfl_xor(l, 32, 64);
        float invl = 1.0f / l;
        int qrow = q0 + lq;
        const float* Lr = Lm + ((size_t)b * NSEQ + qrow) * 16;
        float* ob = out + ((size_t)bh * NSEQ + qrow) * CD;
        #pragma unroll
        for (int cb = 0; cb < 8; ++cb) {
            int c0 = cb * 16 + quad * 4;
            float o0 = oacc[cb].x*invl, o1 = oacc[cb].y*invl;
            float o2 = oacc[cb].z*invl, o3 = oacc[cb].w*invl;
            float4 r;
            if (c0 >= 8) {
                r.x = Lr[0] *o0 + Lr[1] *o1 + Lr[2] *o2 + Lr[3] *o3;
                r.y = Lr[4] *o0 + Lr[5] *o1 + Lr[6] *o2 + Lr[7] *o3;
                r.z = Lr[8] *o0 + Lr[9] *o1 + Lr[10]*o2 + Lr[11]*o3;
                r.w = Lr[12]*o0 + Lr[13]*o1 + Lr[14]*o2 + Lr[15]*o3;
            } else {
                r.x = o0; r.y = o1; r.z = o2; r.w = o3;
            }
            *(float4*)(ob + c0) = r;
        }
    }
}

extern "C" void kernel_launch(void* const* d_in, const int* in_sizes, int n_in,
                              void* d_out, int out_size, void* d_ws, size_t ws_size,
                              hipStream_t stream) {
    const float* q = (const float*)d_in[0];
    const float* k = (const float*)d_in[1];
    const float* v = (const float*)d_in[2];
    const float* L = (const float*)d_in[3];
    float* o = (float*)d_out;
    f16* khs = (f16*)d_ws;                       // 16.78 MB
    f16* vhs = khs + (size_t)64 * 131072;        // 16.78 MB
    dim3 grid1(64, 16);
    ipa_pre<<<grid1, 256, 0, stream>>>(k, v, L, khs, vhs);
    ipa_attn<<<1024, 256, 0, stream>>>(q, khs, vhs, L, o);
}